// Round 10
// baseline (44.442 us; speedup 1.0000x reference)
//
#include <hip/hip_runtime.h>
#include <hip/hip_bf16.h>

typedef __bf16 bf16x8 __attribute__((ext_vector_type(8)));
typedef float f32x16 __attribute__((ext_vector_type(16)));

constexpr int NROW = 8192;
constexpr int DCOL = 256;
constexpr int BMR = 128;                   // block tile rows
constexpr int BNC = 256;                   // block tile cols
constexpr int BK = 32;                     // K-slab; 8 K-tiles over D=256
constexpr int NKT = DCOL / BK;             // 8
constexpr int NRT = NROW / BMR;            // 64 row-tiles
constexpr int NCT = NROW / BNC;            // 32 col-tiles
constexpr int NTILES = 1056;               // sum_{bi<64} (32 - (bi>>1)); 1056 % 8 == 0
constexpr float MARGIN = 0.3f;

// async global->LDS, 16B per lane; LDS dest is wave-uniform base (HW adds lane*16)
__device__ inline void gload16(const unsigned short* g, unsigned short* l) {
    __builtin_amdgcn_global_load_lds(
        (const __attribute__((address_space(1))) void*)g,
        (__attribute__((address_space(3))) void*)l, 16, 0, 0);
}

// ---------------- normalize rows -> bf16 ----------------
__global__ __launch_bounds__(256) void normalize_kernel(const float* __restrict__ hidden,
                                                        unsigned short* __restrict__ xn) {
    int wid = threadIdx.x >> 6, lane = threadIdx.x & 63;
    int row = (blockIdx.x << 2) + wid;
    const float4* src = reinterpret_cast<const float4*>(hidden + (size_t)row * DCOL);
    float4 v = src[lane];
    float ss = v.x * v.x + v.y * v.y + v.z * v.z + v.w * v.w;
    #pragma unroll
    for (int off = 32; off; off >>= 1) ss += __shfl_down(ss, off);
    ss = __shfl(ss, 0);
    float inv = 1.0f / fmaxf(sqrtf(ss), 1e-8f);
    __hip_bfloat16 b0 = __float2bfloat16(v.x * inv);
    __hip_bfloat16 b1 = __float2bfloat16(v.y * inv);
    __hip_bfloat16 b2 = __float2bfloat16(v.z * inv);
    __hip_bfloat16 b3 = __float2bfloat16(v.w * inv);
    ushort4 o;
    o.x = *reinterpret_cast<unsigned short*>(&b0);
    o.y = *reinterpret_cast<unsigned short*>(&b1);
    o.z = *reinterpret_cast<unsigned short*>(&b2);
    o.w = *reinterpret_cast<unsigned short*>(&b3);
    reinterpret_cast<ushort4*>(xn + (size_t)row * DCOL)[lane] = o;
}

// ---------------- 128x256-tile, 4-wave, acc4x2, BK=32 dbuf-prefetch Gram + pair loss ----------
// reads/MFMA = 0.75 (vs r8's 1.0 which sat exactly at the LDS:MFMA balance point);
// LDS 48KB -> 2 blocks/CU for cross-block latency cover (the r8-vs-r7 lesson).
__global__ __launch_bounds__(256, 2) void pairloss_kernel(const unsigned short* __restrict__ xn,
                                                          const int* __restrict__ labels,
                                                          float* __restrict__ partials) {
    __shared__ unsigned short As[2][BMR * BK];   // 2 x 8KB
    __shared__ unsigned short Bs[2][BNC * BK];   // 2 x 16KB
    __shared__ int lblA[BMR], lblB[BNC];
    __shared__ float wsum[4];

    // XCD-aware bijective swizzle (1056 = 8 * 132)
    int bid = (int)(blockIdx.x & 7) * (NTILES / 8) + (int)(blockIdx.x >> 3);
    // unrank -> (bi, bj) with bj >= bi>>1  (tiles touching the strict upper triangle)
    int bi = 0, rem = bid;
    while (rem >= NCT - (bi >> 1)) { rem -= NCT - (bi >> 1); ++bi; }
    int bj = (bi >> 1) + rem;

    int tid = threadIdx.x;
    int wid = tid >> 6, lane = tid & 63;
    int brow = bi * BMR, bcol = bj * BNC;

    if (tid < BMR) lblA[tid] = labels[brow + tid];
    lblB[tid] = labels[bcol + tid];              // 256 threads cover BNC=256

    f32x16 acc[4][2] = {};                       // wave tile 128(rows) x 64(cols)

    // staging: one gload16 fills 16 rows x 64B at BK=32; lane -> row g*16+(lane>>2)
    int srow = lane >> 2;                        // 0..15
    int schunk = (lane & 3) ^ (srow & 3);        // pre-swizzled 16B chunk (4 chunks/row)
    const unsigned short* gA0 = xn + (size_t)brow * DCOL;
    const unsigned short* gB0 = xn + (size_t)bcol * DCOL;
    int lo = lane & 31, hi = lane >> 5;

    auto stage = [&](int t, int b) {             // 6 VMEM instr/thread per K-tile
        #pragma unroll
        for (int q = 0; q < 6; ++q) {
            int g = wid * 6 + q;                 // 24 groups: 0..7 A (128 rows), 8..23 B (256)
            if (g < 8) {
                gload16(gA0 + (g * 16 + srow) * DCOL + t * BK + schunk * 8,
                        &As[b][g * 16 * BK]);
            } else {
                gload16(gB0 + ((g - 8) * 16 + srow) * DCOL + t * BK + schunk * 8,
                        &Bs[b][(g - 8) * 16 * BK]);
            }
        }
    };
    auto compute = [&](int b) {
        #pragma unroll
        for (int kk = 0; kk < 2; ++kk) {         // K16 sub-steps of BK=32
            bf16x8 af[4], bfr[2];
            int cb = kk * 2 + hi;                // 16B k-chunk 0..3
            #pragma unroll
            for (int m = 0; m < 4; ++m) {
                int r = m * 32 + lo;             // all 128 A-rows
                af[m] = *reinterpret_cast<const bf16x8*>(&As[b][r * BK + ((cb ^ (r & 3)) << 3)]);
            }
            #pragma unroll
            for (int n = 0; n < 2; ++n) {
                int r = wid * 64 + n * 32 + lo;  // this wave's 64 B-rows (cols)
                bfr[n] = *reinterpret_cast<const bf16x8*>(&Bs[b][r * BK + ((cb ^ (r & 3)) << 3)]);
            }
            __builtin_amdgcn_s_setprio(1);
            #pragma unroll
            for (int m = 0; m < 4; ++m)
                #pragma unroll
                for (int n = 0; n < 2; ++n)
                    acc[m][n] = __builtin_amdgcn_mfma_f32_32x32x16_bf16(af[m], bfr[n], acc[m][n], 0, 0, 0);
            __builtin_amdgcn_s_setprio(0);
        }
    };

    stage(0, 0);                                 // prologue (only exposed wait per block)
    for (int t = 0; t < NKT; ++t) {
        int c = t & 1;
        asm volatile("s_waitcnt vmcnt(0)" ::: "memory");  // tile t's loads are 1 compute old
        __builtin_amdgcn_s_barrier();            // buf[c] valid for all; buf[c^1] readers done
        if (t + 1 < NKT) stage(t + 1, c ^ 1);    // prefetch flies under compute(t)
        compute(c);
    }

    // epilogue: per-pair loss, strict upper triangle
    // 32x32 C/D: col = lane&31, row = (reg&3) + 8*(reg>>2) + 4*(lane>>5)
    float local = 0.0f;
    #pragma unroll
    for (int m = 0; m < 4; ++m) {
        #pragma unroll
        for (int n = 0; n < 2; ++n) {
            #pragma unroll
            for (int g = 0; g < 16; ++g) {
                int crow = (g & 3) + 8 * (g >> 2) + 4 * hi;
                int il = m * 32 + crow;
                int jl = wid * 64 + n * 32 + lo;
                int gi = brow + il, gj = bcol + jl;
                float sim = acc[m][n][g];
                float v = (lblA[il] == lblB[jl]) ? (1.0f - sim) : fmaxf(sim - MARGIN, 0.0f);
                local += (gi < gj) ? v : 0.0f;
            }
        }
    }
    #pragma unroll
    for (int off = 32; off; off >>= 1) local += __shfl_down(local, off);
    if (lane == 0) wsum[wid] = local;
    __syncthreads();
    if (tid == 0) partials[bid] = wsum[0] + wsum[1] + wsum[2] + wsum[3];
}

// ---------------- reduce partials -> loss ----------------
__global__ __launch_bounds__(512) void finalize_kernel(const float* __restrict__ partials,
                                                       float* __restrict__ out) {
    __shared__ float wsum[8];
    int tid = threadIdx.x, wid = tid >> 6, lane = tid & 63;
    float s = 0.0f;
    for (int i = tid; i < NTILES; i += 512) s += partials[i];
    #pragma unroll
    for (int off = 32; off; off >>= 1) s += __shfl_down(s, off);
    if (lane == 0) wsum[wid] = s;
    __syncthreads();
    if (tid == 0) {
        float total = 0.0f;
        #pragma unroll
        for (int w = 0; w < 8; ++w) total += wsum[w];
        out[0] = total * (1.0f / 33550336.0f);   // / (N*(N-1)/2)
    }
}

extern "C" void kernel_launch(void* const* d_in, const int* in_sizes, int n_in,
                              void* d_out, int out_size, void* d_ws, size_t ws_size,
                              hipStream_t stream) {
    const float* hidden = (const float*)d_in[0];
    const int* labels = (const int*)d_in[1];
    float* out = (float*)d_out;

    unsigned short* xn = (unsigned short*)d_ws;                              // 4 MB
    float* partials = (float*)((char*)d_ws + (size_t)NROW * DCOL * 2);       // 1056 floats

    normalize_kernel<<<NROW / 4, 256, 0, stream>>>(hidden, xn);
    pairloss_kernel<<<NTILES, 256, 0, stream>>>(xn, labels, partials);
    finalize_kernel<<<1, 512, 0, stream>>>(partials, out);
}